// Round 1
// baseline (134.708 us; speedup 1.0000x reference)
//
#include <hip/hip_runtime.h>
#include <hip/hip_bf16.h>
#include <stdint.h>

#define NB 256      // batch
#define LQ 128      // question tokens
#define LC 512      // chunk tokens
#define DIM 384     // feature dim
#define TCD 32      // c-tile rows per iteration
#define QP 392      // padded row pitch in shorts (384 + 8) -> 784 B, spreads banks

typedef __attribute__((ext_vector_type(8))) short short8;
typedef __attribute__((ext_vector_type(4))) float f32x4;

__device__ __forceinline__ unsigned short f2bf(float x) {
  union { float f; uint32_t u; } c; c.f = x;
  return (unsigned short)((c.u + 0x7fffu + ((c.u >> 16) & 1u)) >> 16);
}

// One block per batch b. 8 waves (512 threads).
// Phase 1: load+l2norm q rows -> bf16 LDS; accumulate masked pooled-q partials.
// Phase 2: stream c in 32-row tiles: load+l2norm -> bf16 LDS, pooled-c partials,
//          MFMA qn @ cn^T (each wave owns 16 q rows), fold masked col-max into regs.
// Phase 3: reduce row-max across lanes, masked sum over q rows -> late[b];
//          reduce pooled partials -> pooled[ {q,c} ][b][:].
__global__ __launch_bounds__(512, 1)
void fused_pool_late(const float* __restrict__ qtok, const float* __restrict__ ctok,
                     const int* __restrict__ qm, const int* __restrict__ cm,
                     float* __restrict__ pooled, float* __restrict__ late) {
  __shared__ unsigned short s_q[LQ][QP];    // 100352 B
  __shared__ unsigned short s_c[TCD][QP];   // 25088 B
  __shared__ float s_pq[8][DIM];            // 12288 B
  __shared__ float s_pc[8][DIM];            // 12288 B
  __shared__ float s_cnt[2][8];
  __shared__ int   s_cval[TCD];
  __shared__ float s_wsum[8];

  const int b = blockIdx.x;
  const int tid = threadIdx.x;
  const int wave = tid >> 6;
  const int lane = tid & 63;
  const int rA = lane & 15;          // fragment row/col within 16x16 tile
  const int kof = (lane >> 4) * 8;   // fragment k-offset (8 contiguous bf16)

  const float* qb = qtok + (size_t)b * LQ * DIM;
  const float* cb = ctok + (size_t)b * LC * DIM;
  const int* qmb = qm + b * LQ;
  const int* cmb = cm + b * LC;

  // ---------------- phase 1: q rows ----------------
  float pq[6] = {0.f,0.f,0.f,0.f,0.f,0.f};
  float cq = 0.f;
  for (int r0 = 0; r0 < 16; ++r0) {
    const int r = wave * 16 + r0;
    const float* src = qb + r * DIM;
    float v[6], ss = 0.f;
#pragma unroll
    for (int j = 0; j < 6; ++j) { v[j] = src[lane + 64 * j]; ss += v[j] * v[j]; }
#pragma unroll
    for (int o = 32; o; o >>= 1) ss += __shfl_xor(ss, o);
    const float inv = 1.0f / fmaxf(sqrtf(ss), 1e-12f);
    const float fm = (float)qmb[r];
#pragma unroll
    for (int j = 0; j < 6; ++j) {
      s_q[r][lane + 64 * j] = f2bf(v[j] * inv);
      pq[j] = fmaf(v[j], fm, pq[j]);
    }
    cq += fm;
  }
#pragma unroll
  for (int j = 0; j < 6; ++j) s_pq[wave][lane + 64 * j] = pq[j];
  if (lane == 0) s_cnt[0][wave] = cq;

  // ---------------- phase 2: stream c tiles ----------------
  float rm[4] = {-1e9f, -1e9f, -1e9f, -1e9f};  // running row-max (wave's 16 q rows)
  float pc[6] = {0.f,0.f,0.f,0.f,0.f,0.f};
  float cc = 0.f;

  for (int t = 0; t < LC / TCD; ++t) {
    __syncthreads();  // prev MFMA done before s_c overwrite (t=0: q writes done)
#pragma unroll
    for (int r0 = 0; r0 < 4; ++r0) {
      const int r = wave * 4 + r0;
      const int crow = t * TCD + r;
      const float* src = cb + crow * DIM;
      float v[6], ss = 0.f;
#pragma unroll
      for (int j = 0; j < 6; ++j) { v[j] = src[lane + 64 * j]; ss += v[j] * v[j]; }
#pragma unroll
      for (int o = 32; o; o >>= 1) ss += __shfl_xor(ss, o);
      const float inv = 1.0f / fmaxf(sqrtf(ss), 1e-12f);
      const int mk = cmb[crow];
      const float fm = (float)mk;
#pragma unroll
      for (int j = 0; j < 6; ++j) {
        s_c[r][lane + 64 * j] = f2bf(v[j] * inv);
        pc[j] = fmaf(v[j], fm, pc[j]);
      }
      cc += fm;
      if (lane == 0) s_cval[r] = mk;
    }
    __syncthreads();

    // MFMA: wave's A rows = s_q[wave*16 .. +16); B cols = two 16-wide subtiles
    const unsigned short* ap  = &s_q[wave * 16 + rA][kof];
    const unsigned short* bp0 = &s_c[rA][kof];
    const unsigned short* bp1 = &s_c[rA + 16][kof];
    f32x4 acc0 = {0.f,0.f,0.f,0.f};
    f32x4 acc1 = {0.f,0.f,0.f,0.f};
#pragma unroll
    for (int kk = 0; kk < 12; ++kk) {
      short8 a  = *(const short8*)(ap  + kk * 32);
      short8 b0 = *(const short8*)(bp0 + kk * 32);
      short8 b1 = *(const short8*)(bp1 + kk * 32);
      acc0 = __builtin_amdgcn_mfma_f32_16x16x32_bf16(a, b0, acc0, 0, 0, 0);
      acc1 = __builtin_amdgcn_mfma_f32_16x16x32_bf16(a, b1, acc1, 0, 0, 0);
    }
    const bool v0 = s_cval[rA] != 0;
    const bool v1 = s_cval[rA + 16] != 0;
#pragma unroll
    for (int r = 0; r < 4; ++r) {
      const float a0 = v0 ? acc0[r] : -1e9f;
      const float a1 = v1 ? acc1[r] : -1e9f;
      rm[r] = fmaxf(rm[r], fmaxf(a0, a1));
    }
  }

  // ---------------- phase 3: reductions ----------------
#pragma unroll
  for (int j = 0; j < 6; ++j) s_pc[wave][lane + 64 * j] = pc[j];
  if (lane == 0) s_cnt[1][wave] = cc;

  // max across the 16 col-classes (lanes sharing lane>>4)
#pragma unroll
  for (int r = 0; r < 4; ++r) {
#pragma unroll
    for (int o = 1; o < 16; o <<= 1) rm[r] = fmaxf(rm[r], __shfl_xor(rm[r], o));
  }
  // masked sum over this wave's 16 q rows
  float ps = 0.f;
  if (rA == 0) {
    const int rowb = wave * 16 + (lane >> 4) * 4;
#pragma unroll
    for (int r = 0; r < 4; ++r) ps += qmb[rowb + r] ? rm[r] : 0.f;
  }
#pragma unroll
  for (int o = 32; o; o >>= 1) ps += __shfl_xor(ps, o);
  if (lane == 0) s_wsum[wave] = ps;
  __syncthreads();

  if (tid < DIM) {
    float sq = 0.f, sc = 0.f, nq = 0.f, nc = 0.f;
#pragma unroll
    for (int w = 0; w < 8; ++w) {
      sq += s_pq[w][tid];
      sc += s_pc[w][tid];
      nq += s_cnt[0][w];
      nc += s_cnt[1][w];
    }
    pooled[b * DIM + tid] = sq / fmaxf(nq, 1e-9f);
    pooled[(NB + b) * DIM + tid] = sc / fmaxf(nc, 1e-9f);
  }
  if (tid == 0) {
    float tot = 0.f;
#pragma unroll
    for (int w = 0; w < 8; ++w) tot += s_wsum[w];
    late[b] = tot;
  }
}

// One block per pooled row (grid 256 x 2). h = relu(p@W1+b1); e = l2norm(h@W2+b2).
__global__ __launch_bounds__(DIM)
void mlp_kernel(const float* __restrict__ pooled,
                const float* __restrict__ W1, const float* __restrict__ b1,
                const float* __restrict__ W2, const float* __restrict__ b2,
                float* __restrict__ emb) {
  __shared__ float s_in[DIM];
  __shared__ float s_h[DIM];
  __shared__ float s_red[6];
  const int row = blockIdx.y * NB + blockIdx.x;
  const int d = threadIdx.x;
  s_in[d] = pooled[row * DIM + d];
  __syncthreads();
  float acc = b1[d];
#pragma unroll 8
  for (int k = 0; k < DIM; ++k) acc = fmaf(s_in[k], W1[k * DIM + d], acc);
  s_h[d] = fmaxf(acc, 0.f);
  __syncthreads();
  float p = b2[d];
#pragma unroll 8
  for (int k = 0; k < DIM; ++k) p = fmaf(s_h[k], W2[k * DIM + d], p);
  float ss = p * p;
#pragma unroll
  for (int o = 32; o; o >>= 1) ss += __shfl_xor(ss, o);
  if ((d & 63) == 0) s_red[d >> 6] = ss;
  __syncthreads();
  float tot = 0.f;
#pragma unroll
  for (int w = 0; w < 6; ++w) tot += s_red[w];
  emb[row * DIM + d] = p * (1.0f / fmaxf(sqrtf(tot), 1e-12f));
}

// out0[i][j] = dot(q_emb[i], c_emb[j]) / 0.07
__global__ __launch_bounds__(NB)
void contrast_kernel(const float* __restrict__ emb, float* __restrict__ out0) {
  __shared__ float s_q[DIM];
  const int i = blockIdx.x;
  for (int k = threadIdx.x; k < DIM; k += NB) s_q[k] = emb[i * DIM + k];
  __syncthreads();
  const float* ce = emb + (size_t)(NB + threadIdx.x) * DIM;
  float acc = 0.f;
#pragma unroll 8
  for (int k = 0; k < DIM; ++k) acc = fmaf(s_q[k], ce[k], acc);
  out0[i * NB + threadIdx.x] = acc / 0.07f;
}

extern "C" void kernel_launch(void* const* d_in, const int* in_sizes, int n_in,
                              void* d_out, int out_size, void* d_ws, size_t ws_size,
                              hipStream_t stream) {
  const float* qtok = (const float*)d_in[0];
  const float* ctok = (const float*)d_in[1];
  const int*   qmm  = (const int*)d_in[2];
  const int*   cmm  = (const int*)d_in[3];
  const float* W1   = (const float*)d_in[4];
  const float* b1   = (const float*)d_in[5];
  const float* W2   = (const float*)d_in[6];
  const float* b2   = (const float*)d_in[7];

  float* out0 = (float*)d_out;           // [NB*NB]
  float* late = out0 + NB * NB;          // [NB]
  float* pooled = (float*)d_ws;          // [2*NB*DIM]
  float* emb    = pooled + 2 * NB * DIM; // [2*NB*DIM]

  hipLaunchKernelGGL(fused_pool_late, dim3(NB), dim3(512), 0, stream,
                     qtok, ctok, qmm, cmm, pooled, late);
  hipLaunchKernelGGL(mlp_kernel, dim3(NB, 2), dim3(DIM), 0, stream,
                     pooled, W1, b1, W2, b2, emb);
  hipLaunchKernelGGL(contrast_kernel, dim3(NB), dim3(NB), 0, stream, emb, out0);
}